// Round 1
// baseline (7437.193 us; speedup 1.0000x reference)
//
#include <hip/hip_runtime.h>

#define NN 50000
#define NE 800000
#define DD 128
#define NHD 16
#define EFD 16
#define RFD 64
#define KVD 336

#define ME 64
#define BK 16
#define HS 260   // hid LDS row stride (256 + 4 pad)

// ---------------------------------------------------------------------------
// Kernel 1: q = MLP_xq(h)   (Linear 128->128, LN, ReLU, Linear 128->128)
// 4 nodes per 128-thread block.
// ---------------------------------------------------------------------------
__global__ __launch_bounds__(128) void qmlp_kernel(
    const float* __restrict__ h,
    const float* __restrict__ W1, const float* __restrict__ b1,
    const float* __restrict__ g,  const float* __restrict__ be,
    const float* __restrict__ W2, const float* __restrict__ b2,
    float* __restrict__ q)
{
    __shared__ float hs[4][DD];
    __shared__ float hid[4][DD];
    __shared__ float red[4][2][2];
    const int j  = threadIdx.x;
    const int n0 = blockIdx.x * 4;

    #pragma unroll
    for (int n = 0; n < 4; n++) hs[n][j] = h[(size_t)(n0 + n) * DD + j];
    __syncthreads();

    float a[4];
    #pragma unroll
    for (int n = 0; n < 4; n++) a[n] = b1[j];
    #pragma unroll 8
    for (int i = 0; i < DD; i++) {
        float w = W1[i * DD + j];
        #pragma unroll
        for (int n = 0; n < 4; n++) a[n] = fmaf(hs[n][i], w, a[n]);
    }

    const int wid = j >> 6;
    #pragma unroll
    for (int n = 0; n < 4; n++) {
        float s1 = a[n], s2 = a[n] * a[n];
        #pragma unroll
        for (int off = 32; off > 0; off >>= 1) {
            s1 += __shfl_xor(s1, off);
            s2 += __shfl_xor(s2, off);
        }
        if ((j & 63) == 0) { red[n][0][wid] = s1; red[n][1][wid] = s2; }
    }
    __syncthreads();

    const float gg = g[j], bb = be[j];
    #pragma unroll
    for (int n = 0; n < 4; n++) {
        float s1   = red[n][0][0] + red[n][0][1];
        float s2   = red[n][1][0] + red[n][1][1];
        float mean = s1 * (1.0f / DD);
        float var  = s2 * (1.0f / DD) - mean * mean;
        float r    = (a[n] - mean) * rsqrtf(var + 1e-5f) * gg + bb;
        hid[n][j]  = fmaxf(r, 0.0f);
    }
    __syncthreads();

    float o[4];
    #pragma unroll
    for (int n = 0; n < 4; n++) o[n] = b2[j];
    #pragma unroll 8
    for (int i = 0; i < DD; i++) {
        float w = W2[i * DD + j];
        #pragma unroll
        for (int n = 0; n < 4; n++) o[n] = fmaf(hid[n][i], w, o[n]);
    }
    #pragma unroll
    for (int n = 0; n < 4; n++) q[(size_t)(n0 + n) * DD + j] = o[n];
}

// ---------------------------------------------------------------------------
// Kernel 2: per-edge pipeline. 64 edges / block, 256 threads.
//  GEMM1 (kv[64,336] @ [336,256] both W1s) -> LN -> ReLU -> LDS
//  GEMM2 k (128x128) in registers, v (128x16), e_w, s = q.k, exp, atomics
// ---------------------------------------------------------------------------
struct Stage {
    float kv[BK][68];     // [k][edge], padded
    float w[BK][256];     // [k][col]  cols 0..127 xk_W1, 128..255 xv_W1
};
union SharedU {
    Stage s1;
    float hid[ME * HS];   // 66560 B
};

__global__ __launch_bounds__(256) void edge_kernel(
    const float* __restrict__ h,
    const float* __restrict__ rel_x,
    const float* __restrict__ r_feat,
    const float* __restrict__ edge_feat,
    const int*   __restrict__ e_src,
    const int*   __restrict__ e_dst,
    const float* __restrict__ xk_W1, const float* __restrict__ xk_b1,
    const float* __restrict__ xk_g,  const float* __restrict__ xk_be,
    const float* __restrict__ xk_W2, const float* __restrict__ xk_b2,
    const float* __restrict__ xv_W1, const float* __restrict__ xv_b1,
    const float* __restrict__ xv_g,  const float* __restrict__ xv_be,
    const float* __restrict__ xv_W2, const float* __restrict__ xv_b2,
    const float* __restrict__ ew_W,  const float* __restrict__ ew_b,
    const float* __restrict__ q,
    float* __restrict__ accN)     // [NN][NHD][4] = {x,y,z,den}
{
    __shared__ SharedU u;
    __shared__ float v_s[ME][NHD];
    __shared__ float ew_s[ME];
    __shared__ float rel_s[ME][3];
    __shared__ int   dst_s[ME];
    __shared__ int   src_s[ME];

    const int tid = threadIdx.x;
    const int e0  = blockIdx.x * ME;

    // --- stage indices / rel_x ---
    if (tid < ME) { dst_s[tid] = e_dst[e0 + tid]; src_s[tid] = e_src[e0 + tid]; }
    else {
        int t = tid - ME;   // 0..191
        rel_s[t / 3][t % 3] = rel_x[(size_t)e0 * 3 + t];
    }

    // --- e_w = sigmoid(r_feat @ ew_W + b), 4 threads/edge ---
    {
        int edge = tid >> 2, part = tid & 3;
        const float* rp = &r_feat[(size_t)(e0 + edge) * RFD + part * 16];
        const float* wp = &ew_W[part * 16];
        float p = 0.0f;
        #pragma unroll
        for (int jj = 0; jj < 16; jj++) p = fmaf(rp[jj], wp[jj], p);
        p += __shfl_xor(p, 1);
        p += __shfl_xor(p, 2);
        if (part == 0) ew_s[edge] = 1.0f / (1.0f + expf(-(p + ew_b[0])));
    }
    __syncthreads();

    // --- GEMM1: 64 edges x 256 cols, K = 336 ---
    const int tc = tid & 31;   // col group: cols tc*8 .. tc*8+7
    const int te = tid >> 5;   // edge group: edges te*8 .. te*8+7
    float acc[8][8];
    #pragma unroll
    for (int e = 0; e < 8; e++)
        #pragma unroll
        for (int c = 0; c < 8; c++) acc[e][c] = 0.0f;

    for (int kc = 0; kc < KVD / BK; kc++) {
        const int kbase = kc * BK;
        // stage kv chunk: 16 cols x 64 edges (source uniform per chunk)
        {
            int col = tid & 15;
            int el0 = tid >> 4;
            int kcol = kbase + col;
            #pragma unroll
            for (int pass = 0; pass < 4; pass++) {
                int el = el0 + pass * 16;
                size_t e = (size_t)(e0 + el);
                float val;
                if (kcol < EFD)            val = edge_feat[e * EFD + kcol];
                else if (kcol < EFD + RFD) val = r_feat[e * RFD + (kcol - EFD)];
                else if (kcol < EFD + RFD + DD)
                    val = h[(size_t)dst_s[el] * DD + (kcol - (EFD + RFD))];
                else
                    val = h[(size_t)src_s[el] * DD + (kcol - (EFD + RFD + DD))];
                u.s1.kv[col][el] = val;
            }
        }
        // stage W chunk: both matrices
        {
            int halfw = tid >> 7;
            int cid   = tid & 127;
            const float* Wsrc = halfw ? xv_W1 : xk_W1;
            #pragma unroll
            for (int kk = 0; kk < BK; kk++)
                u.s1.w[kk][halfw * 128 + cid] = Wsrc[(kbase + kk) * 128 + cid];
        }
        __syncthreads();
        #pragma unroll
        for (int kk = 0; kk < BK; kk++) {
            const float4 w0 = *(const float4*)&u.s1.w[kk][tc * 8];
            const float4 w1 = *(const float4*)&u.s1.w[kk][tc * 8 + 4];
            const float4 a0 = *(const float4*)&u.s1.kv[kk][te * 8];
            const float4 a1 = *(const float4*)&u.s1.kv[kk][te * 8 + 4];
            const float wv[8] = {w0.x, w0.y, w0.z, w0.w, w1.x, w1.y, w1.z, w1.w};
            const float av[8] = {a0.x, a0.y, a0.z, a0.w, a1.x, a1.y, a1.z, a1.w};
            #pragma unroll
            for (int e = 0; e < 8; e++)
                #pragma unroll
                for (int c = 0; c < 8; c++)
                    acc[e][c] = fmaf(av[e], wv[c], acc[e][c]);
        }
        __syncthreads();
    }

    // --- bias + LayerNorm + ReLU (16-lane shfl groups) ---
    {
        const int halfsel = tc >> 4;
        const int lcol    = (tc * 8) & 127;
        const float* b1p = halfsel ? xv_b1 : xk_b1;
        const float* gp  = halfsel ? xv_g  : xk_g;
        const float* bep = halfsel ? xv_be : xk_be;
        float bias[8], gv[8], bev[8];
        #pragma unroll
        for (int c = 0; c < 8; c++) {
            bias[c] = b1p[lcol + c];
            gv[c]   = gp[lcol + c];
            bev[c]  = bep[lcol + c];
        }
        #pragma unroll
        for (int e = 0; e < 8; e++) {
            float s1 = 0.0f, s2 = 0.0f;
            #pragma unroll
            for (int c = 0; c < 8; c++) {
                float x = acc[e][c] + bias[c];
                acc[e][c] = x;
                s1 += x; s2 = fmaf(x, x, s2);
            }
            #pragma unroll
            for (int off = 1; off < 16; off <<= 1) {
                s1 += __shfl_xor(s1, off);
                s2 += __shfl_xor(s2, off);
            }
            float mean = s1 * (1.0f / 128.0f);
            float var  = s2 * (1.0f / 128.0f) - mean * mean;
            float rstd = rsqrtf(var + 1e-5f);
            #pragma unroll
            for (int c = 0; c < 8; c++) {
                float r = (acc[e][c] - mean) * rstd * gv[c] + bev[c];
                acc[e][c] = fmaxf(r, 0.0f);
            }
        }
    }

    // --- store hidden to LDS (aliases stage buffers; last sync already done) ---
    #pragma unroll
    for (int e = 0; e < 8; e++) {
        float4 p0 = make_float4(acc[e][0], acc[e][1], acc[e][2], acc[e][3]);
        float4 p1 = make_float4(acc[e][4], acc[e][5], acc[e][6], acc[e][7]);
        *(float4*)&u.hid[(te * 8 + e) * HS + tc * 8]     = p0;
        *(float4*)&u.hid[(te * 8 + e) * HS + tc * 8 + 4] = p1;
    }
    __syncthreads();

    // --- GEMM2 k-net: k[64][128], thread = 8 edges x 4 cols, k stays in regs ---
    const int tc2 = tid & 31;   // cols tc2*4 .. +3
    const int te2 = tid >> 5;   // edges te2*8 .. +7
    float k_acc[8][4];
    {
        const float4 b2v = *(const float4*)&xk_b2[tc2 * 4];
        #pragma unroll
        for (int e = 0; e < 8; e++) {
            k_acc[e][0] = b2v.x; k_acc[e][1] = b2v.y;
            k_acc[e][2] = b2v.z; k_acc[e][3] = b2v.w;
        }
        #pragma unroll 4
        for (int i = 0; i < 128; i++) {
            const float4 w = *(const float4*)&xk_W2[i * 128 + tc2 * 4];
            #pragma unroll
            for (int e = 0; e < 8; e++) {
                float hv = u.hid[(te2 * 8 + e) * HS + i];
                k_acc[e][0] = fmaf(hv, w.x, k_acc[e][0]);
                k_acc[e][1] = fmaf(hv, w.y, k_acc[e][1]);
                k_acc[e][2] = fmaf(hv, w.z, k_acc[e][2]);
                k_acc[e][3] = fmaf(hv, w.w, k_acc[e][3]);
            }
        }
    }

    // --- v-net: v[64][16], 4 items/thread ---
    #pragma unroll
    for (int p = 0; p < 4; p++) {
        int item = tid + p * 256;
        int e    = item >> 4;
        int col  = item & 15;
        float a = xv_b2[col];
        #pragma unroll 4
        for (int i = 0; i < 128; i++)
            a = fmaf(u.hid[e * HS + 128 + i], xv_W2[i * 16 + col], a);
        v_s[e][col] = a;
    }
    __syncthreads();

    // --- attention scores + scatter accumulate ---
    {
        const float inv_s8 = 0.35355339059327373f; // 1/sqrt(8)
        const int head = tc2 >> 1;
        const int sub  = tc2 & 1;
        #pragma unroll
        for (int e = 0; e < 8; e++) {
            int el  = te2 * 8 + e;
            int dst = dst_s[el];
            const float4 qv = *(const float4*)&q[(size_t)dst * DD + tc2 * 4];
            float p = qv.x * k_acc[e][0] + qv.y * k_acc[e][1] +
                      qv.z * k_acc[e][2] + qv.w * k_acc[e][3];
            p += __shfl_xor(p, 1);
            if (sub == 0) {
                float ex = expf(p * inv_s8);
                float vw = v_s[el][head] * ew_s[el] * ex;
                float* base = &accN[(((size_t)dst * NHD) + head) * 4];
                atomicAdd(base + 0, vw * rel_s[el][0]);
                atomicAdd(base + 1, vw * rel_s[el][1]);
                atomicAdd(base + 2, vw * rel_s[el][2]);
                atomicAdd(base + 3, ex);
            }
        }
    }
}

// ---------------------------------------------------------------------------
// Kernel 3: out[n] = mean_h num[n][h]/den[n][h]
// ---------------------------------------------------------------------------
__global__ __launch_bounds__(256) void finalize_kernel(
    const float* __restrict__ accN, float* __restrict__ out)
{
    int n = blockIdx.x * blockDim.x + threadIdx.x;
    if (n >= NN) return;
    float ox = 0.0f, oy = 0.0f, oz = 0.0f;
    #pragma unroll
    for (int hh = 0; hh < NHD; hh++) {
        float4 a = *(const float4*)&accN[(((size_t)n * NHD) + hh) * 4];
        if (a.w > 0.0f) {
            float r = 1.0f / a.w;
            ox = fmaf(a.x, r, ox);
            oy = fmaf(a.y, r, oy);
            oz = fmaf(a.z, r, oz);
        }
    }
    out[n * 3 + 0] = ox * (1.0f / NHD);
    out[n * 3 + 1] = oy * (1.0f / NHD);
    out[n * 3 + 2] = oz * (1.0f / NHD);
}

extern "C" void kernel_launch(void* const* d_in, const int* in_sizes, int n_in,
                              void* d_out, int out_size, void* d_ws, size_t ws_size,
                              hipStream_t stream)
{
    const float* h         = (const float*)d_in[0];
    const float* rel_x     = (const float*)d_in[1];
    const float* r_feat    = (const float*)d_in[2];
    const float* edge_feat = (const float*)d_in[3];
    const int*   e_idx     = (const int*)d_in[4];
    const float* xk_W1 = (const float*)d_in[5];
    const float* xk_b1 = (const float*)d_in[6];
    const float* xk_g  = (const float*)d_in[7];
    const float* xk_be = (const float*)d_in[8];
    const float* xk_W2 = (const float*)d_in[9];
    const float* xk_b2 = (const float*)d_in[10];
    const float* xv_W1 = (const float*)d_in[11];
    const float* xv_b1 = (const float*)d_in[12];
    const float* xv_g  = (const float*)d_in[13];
    const float* xv_be = (const float*)d_in[14];
    const float* xv_W2 = (const float*)d_in[15];
    const float* xv_b2 = (const float*)d_in[16];
    const float* xq_W1 = (const float*)d_in[17];
    const float* xq_b1 = (const float*)d_in[18];
    const float* xq_g  = (const float*)d_in[19];
    const float* xq_be = (const float*)d_in[20];
    const float* xq_W2 = (const float*)d_in[21];
    const float* xq_b2 = (const float*)d_in[22];
    const float* ew_W  = (const float*)d_in[23];
    const float* ew_b  = (const float*)d_in[24];

    float* q    = (float*)d_ws;                 // NN*128 floats
    float* accN = q + (size_t)NN * DD;          // NN*16*4 floats

    hipMemsetAsync(accN, 0, (size_t)NN * NHD * 4 * sizeof(float), stream);

    qmlp_kernel<<<NN / 4, 128, 0, stream>>>(h, xq_W1, xq_b1, xq_g, xq_be,
                                            xq_W2, xq_b2, q);

    edge_kernel<<<NE / ME, 256, 0, stream>>>(
        h, rel_x, r_feat, edge_feat,
        e_idx, e_idx + NE,
        xk_W1, xk_b1, xk_g, xk_be, xk_W2, xk_b2,
        xv_W1, xv_b1, xv_g, xv_be, xv_W2, xv_b2,
        ew_W, ew_b, q, accN);

    finalize_kernel<<<(NN + 255) / 256, 256, 0, stream>>>(accN, (float*)d_out);
}

// Round 2
// 6264.632 us; speedup vs baseline: 1.1872x; 1.1872x over previous
//
#include <hip/hip_runtime.h>

#define NN 50000
#define NE 800000
#define DD 128
#define NHD 16
#define EFD 16
#define RFD 64
#define KVD 336

#define ME 64
#define BK 16
#define HPAD 132   // hid LDS row stride (128 + 4 pad)

// ---------------------------------------------------------------------------
// Kernel 1: q = MLP_xq(h)   (Linear 128->128, LN, ReLU, Linear 128->128)
// 4 nodes per 128-thread block.
// ---------------------------------------------------------------------------
__global__ __launch_bounds__(128) void qmlp_kernel(
    const float* __restrict__ h,
    const float* __restrict__ W1, const float* __restrict__ b1,
    const float* __restrict__ g,  const float* __restrict__ be,
    const float* __restrict__ W2, const float* __restrict__ b2,
    float* __restrict__ q)
{
    __shared__ float hs[4][DD];
    __shared__ float hid[4][DD];
    __shared__ float red[4][2][2];
    const int j  = threadIdx.x;
    const int n0 = blockIdx.x * 4;

    #pragma unroll
    for (int n = 0; n < 4; n++) hs[n][j] = h[(size_t)(n0 + n) * DD + j];
    __syncthreads();

    float a[4];
    #pragma unroll
    for (int n = 0; n < 4; n++) a[n] = b1[j];
    #pragma unroll 8
    for (int i = 0; i < DD; i++) {
        float w = W1[i * DD + j];
        #pragma unroll
        for (int n = 0; n < 4; n++) a[n] = fmaf(hs[n][i], w, a[n]);
    }

    const int wid = j >> 6;
    #pragma unroll
    for (int n = 0; n < 4; n++) {
        float s1 = a[n], s2 = a[n] * a[n];
        #pragma unroll
        for (int off = 32; off > 0; off >>= 1) {
            s1 += __shfl_xor(s1, off);
            s2 += __shfl_xor(s2, off);
        }
        if ((j & 63) == 0) { red[n][0][wid] = s1; red[n][1][wid] = s2; }
    }
    __syncthreads();

    const float gg = g[j], bb = be[j];
    #pragma unroll
    for (int n = 0; n < 4; n++) {
        float s1   = red[n][0][0] + red[n][0][1];
        float s2   = red[n][1][0] + red[n][1][1];
        float mean = s1 * (1.0f / DD);
        float var  = s2 * (1.0f / DD) - mean * mean;
        float r    = (a[n] - mean) * rsqrtf(var + 1e-5f) * gg + bb;
        hid[n][j]  = fmaxf(r, 0.0f);
    }
    __syncthreads();

    float o[4];
    #pragma unroll
    for (int n = 0; n < 4; n++) o[n] = b2[j];
    #pragma unroll 8
    for (int i = 0; i < DD; i++) {
        float w = W2[i * DD + j];
        #pragma unroll
        for (int n = 0; n < 4; n++) o[n] = fmaf(hid[n][i], w, o[n]);
    }
    #pragma unroll
    for (int n = 0; n < 4; n++) q[(size_t)(n0 + n) * DD + j] = o[n];
}

// ---------------------------------------------------------------------------
// Kernel 2: per-edge pipeline. 64 edges / block, 256 threads.
// Thread (te = tid>>5, tc = tid&31) owns edges te*8..+7 and cols
// {tc*4..+3} (xk) + {128+tc*4..+3} (xv): lane stride 16B -> conflict-free
// b128 LDS access. kv reads are wave-broadcast (free).
// hid buffer holds one 64x128 half at a time (xk half -> GEMM2-k ->
// reuse for xv half -> v-net), keeping LDS under 40KB -> 4 blocks/CU.
// ---------------------------------------------------------------------------
struct Stage {
    float kv[BK][68];     // [k][edge], padded
    float w[BK][256];     // [k][col]  cols 0..127 xk_W1, 128..255 xv_W1
};
union SharedU {
    Stage s1;             // 20736 B
    float hid[ME * HPAD]; // 33792 B
};

__global__ __launch_bounds__(256, 4) void edge_kernel(
    const float* __restrict__ h,
    const float* __restrict__ rel_x,
    const float* __restrict__ r_feat,
    const float* __restrict__ edge_feat,
    const int*   __restrict__ e_src,
    const int*   __restrict__ e_dst,
    const float* __restrict__ xk_W1, const float* __restrict__ xk_b1,
    const float* __restrict__ xk_g,  const float* __restrict__ xk_be,
    const float* __restrict__ xk_W2, const float* __restrict__ xk_b2,
    const float* __restrict__ xv_W1, const float* __restrict__ xv_b1,
    const float* __restrict__ xv_g,  const float* __restrict__ xv_be,
    const float* __restrict__ xv_W2, const float* __restrict__ xv_b2,
    const float* __restrict__ ew_W,  const float* __restrict__ ew_b,
    const float* __restrict__ q,
    float* __restrict__ accN)     // [NN][NHD][4] = {x,y,z,den}
{
    __shared__ SharedU u;
    __shared__ float v_s[ME][NHD];
    __shared__ float ew_s[ME];
    __shared__ float rel_s[ME][3];
    __shared__ int   dst_s[ME];
    __shared__ int   src_s[ME];

    const int tid = threadIdx.x;
    const int e0  = blockIdx.x * ME;

    // --- stage indices / rel_x ---
    if (tid < ME) { dst_s[tid] = e_dst[e0 + tid]; src_s[tid] = e_src[e0 + tid]; }
    else {
        int t = tid - ME;   // 0..191
        rel_s[t / 3][t % 3] = rel_x[(size_t)e0 * 3 + t];
    }

    // --- e_w = sigmoid(r_feat @ ew_W + b), 4 threads/edge ---
    {
        int edge = tid >> 2, part = tid & 3;
        const float* rp = &r_feat[(size_t)(e0 + edge) * RFD + part * 16];
        const float* wp = &ew_W[part * 16];
        float p = 0.0f;
        #pragma unroll
        for (int jj = 0; jj < 16; jj++) p = fmaf(rp[jj], wp[jj], p);
        p += __shfl_xor(p, 1);
        p += __shfl_xor(p, 2);
        if (part == 0) ew_s[edge] = 1.0f / (1.0f + expf(-(p + ew_b[0])));
    }
    __syncthreads();

    // --- GEMM1: 64 edges x 256 cols, K = 336 ---
    const int tc = tid & 31;   // col group: {tc*4..+3, 128+tc*4..+3}
    const int te = tid >> 5;   // edge group: edges te*8 .. te*8+7
    float acc[8][8];           // [e][0..3]=xk cols, [e][4..7]=xv cols
    #pragma unroll
    for (int e = 0; e < 8; e++)
        #pragma unroll
        for (int c = 0; c < 8; c++) acc[e][c] = 0.0f;

    for (int kc = 0; kc < KVD / BK; kc++) {
        const int kbase = kc * BK;
        // stage kv chunk: 16 cols x 64 edges (source uniform per chunk)
        {
            int col = tid & 15;
            int el0 = tid >> 4;
            int kcol = kbase + col;
            #pragma unroll
            for (int pass = 0; pass < 4; pass++) {
                int el = el0 + pass * 16;
                size_t e = (size_t)(e0 + el);
                float val;
                if (kcol < EFD)            val = edge_feat[e * EFD + kcol];
                else if (kcol < EFD + RFD) val = r_feat[e * RFD + (kcol - EFD)];
                else if (kcol < EFD + RFD + DD)
                    val = h[(size_t)dst_s[el] * DD + (kcol - (EFD + RFD))];
                else
                    val = h[(size_t)src_s[el] * DD + (kcol - (EFD + RFD + DD))];
                u.s1.kv[col][el] = val;
            }
        }
        // stage W chunk: both matrices (consecutive lanes -> consecutive cols)
        {
            int halfw = tid >> 7;
            int cid   = tid & 127;
            const float* Wsrc = halfw ? xv_W1 : xk_W1;
            #pragma unroll
            for (int kk = 0; kk < BK; kk++)
                u.s1.w[kk][halfw * 128 + cid] = Wsrc[(kbase + kk) * 128 + cid];
        }
        __syncthreads();
        #pragma unroll
        for (int kk = 0; kk < BK; kk++) {
            // w reads: lane stride 16B -> conflict-free
            const float4 w0 = *(const float4*)&u.s1.w[kk][tc * 4];
            const float4 w1 = *(const float4*)&u.s1.w[kk][128 + tc * 4];
            // kv reads: wave-broadcast
            const float4 a0 = *(const float4*)&u.s1.kv[kk][te * 8];
            const float4 a1 = *(const float4*)&u.s1.kv[kk][te * 8 + 4];
            const float wv[8] = {w0.x, w0.y, w0.z, w0.w, w1.x, w1.y, w1.z, w1.w};
            const float av[8] = {a0.x, a0.y, a0.z, a0.w, a1.x, a1.y, a1.z, a1.w};
            #pragma unroll
            for (int e = 0; e < 8; e++)
                #pragma unroll
                for (int c = 0; c < 8; c++)
                    acc[e][c] = fmaf(av[e], wv[c], acc[e][c]);
        }
        __syncthreads();
    }

    // --- bias + LayerNorm + ReLU (32-lane shfl groups, xk & xv together) ---
    {
        float bk[4], gk[4], bek[4], bv[4], gv[4], bev[4];
        #pragma unroll
        for (int c = 0; c < 4; c++) {
            bk[c]  = xk_b1[tc * 4 + c];
            gk[c]  = xk_g [tc * 4 + c];
            bek[c] = xk_be[tc * 4 + c];
            bv[c]  = xv_b1[tc * 4 + c];
            gv[c]  = xv_g [tc * 4 + c];
            bev[c] = xv_be[tc * 4 + c];
        }
        #pragma unroll
        for (int e = 0; e < 8; e++) {
            float sk1 = 0.0f, sk2 = 0.0f, sv1 = 0.0f, sv2 = 0.0f;
            #pragma unroll
            for (int c = 0; c < 4; c++) {
                float xk = acc[e][c] + bk[c];
                float xv = acc[e][4 + c] + bv[c];
                acc[e][c] = xk; acc[e][4 + c] = xv;
                sk1 += xk; sk2 = fmaf(xk, xk, sk2);
                sv1 += xv; sv2 = fmaf(xv, xv, sv2);
            }
            #pragma unroll
            for (int off = 1; off < 32; off <<= 1) {
                sk1 += __shfl_xor(sk1, off);
                sk2 += __shfl_xor(sk2, off);
                sv1 += __shfl_xor(sv1, off);
                sv2 += __shfl_xor(sv2, off);
            }
            float mk = sk1 * (1.0f / 128.0f);
            float vk = sk2 * (1.0f / 128.0f) - mk * mk;
            float rk = rsqrtf(vk + 1e-5f);
            float mv = sv1 * (1.0f / 128.0f);
            float vv = sv2 * (1.0f / 128.0f) - mv * mv;
            float rv = rsqrtf(vv + 1e-5f);
            #pragma unroll
            for (int c = 0; c < 4; c++) {
                acc[e][c]     = fmaxf((acc[e][c]     - mk) * rk * gk[c] + bek[c], 0.0f);
                acc[e][4 + c] = fmaxf((acc[e][4 + c] - mv) * rv * gv[c] + bev[c], 0.0f);
            }
        }
    }

    // --- store xk-half hidden to LDS (conflict-free b128) ---
    #pragma unroll
    for (int e = 0; e < 8; e++)
        *(float4*)&u.hid[(te * 8 + e) * HPAD + tc * 4] =
            make_float4(acc[e][0], acc[e][1], acc[e][2], acc[e][3]);
    __syncthreads();

    // --- GEMM2 k-net: k[64][128], thread = 8 edges x 4 cols ---
    const int tc2 = tid & 31;   // cols tc2*4 .. +3
    const int te2 = tid >> 5;   // edges te2*8 .. +7
    float k_acc[8][4];
    {
        const float4 b2v = *(const float4*)&xk_b2[tc2 * 4];
        #pragma unroll
        for (int e = 0; e < 8; e++) {
            k_acc[e][0] = b2v.x; k_acc[e][1] = b2v.y;
            k_acc[e][2] = b2v.z; k_acc[e][3] = b2v.w;
        }
        #pragma unroll 4
        for (int i4 = 0; i4 < 32; i4++) {
            const float4 w0 = *(const float4*)&xk_W2[(i4 * 4 + 0) * 128 + tc2 * 4];
            const float4 w1 = *(const float4*)&xk_W2[(i4 * 4 + 1) * 128 + tc2 * 4];
            const float4 w2 = *(const float4*)&xk_W2[(i4 * 4 + 2) * 128 + tc2 * 4];
            const float4 w3 = *(const float4*)&xk_W2[(i4 * 4 + 3) * 128 + tc2 * 4];
            #pragma unroll
            for (int e = 0; e < 8; e++) {
                const float4 hv = *(const float4*)&u.hid[(te2 * 8 + e) * HPAD + i4 * 4];
                k_acc[e][0] = fmaf(hv.x, w0.x, k_acc[e][0]);
                k_acc[e][1] = fmaf(hv.x, w0.y, k_acc[e][1]);
                k_acc[e][2] = fmaf(hv.x, w0.z, k_acc[e][2]);
                k_acc[e][3] = fmaf(hv.x, w0.w, k_acc[e][3]);
                k_acc[e][0] = fmaf(hv.y, w1.x, k_acc[e][0]);
                k_acc[e][1] = fmaf(hv.y, w1.y, k_acc[e][1]);
                k_acc[e][2] = fmaf(hv.y, w1.z, k_acc[e][2]);
                k_acc[e][3] = fmaf(hv.y, w1.w, k_acc[e][3]);
                k_acc[e][0] = fmaf(hv.z, w2.x, k_acc[e][0]);
                k_acc[e][1] = fmaf(hv.z, w2.y, k_acc[e][1]);
                k_acc[e][2] = fmaf(hv.z, w2.z, k_acc[e][2]);
                k_acc[e][3] = fmaf(hv.z, w2.w, k_acc[e][3]);
                k_acc[e][0] = fmaf(hv.w, w3.x, k_acc[e][0]);
                k_acc[e][1] = fmaf(hv.w, w3.y, k_acc[e][1]);
                k_acc[e][2] = fmaf(hv.w, w3.z, k_acc[e][2]);
                k_acc[e][3] = fmaf(hv.w, w3.w, k_acc[e][3]);
            }
        }
    }
    __syncthreads();   // all GEMM2-k reads done before hid overwrite

    // --- store xv-half hidden into the same LDS buffer ---
    #pragma unroll
    for (int e = 0; e < 8; e++)
        *(float4*)&u.hid[(te * 8 + e) * HPAD + tc * 4] =
            make_float4(acc[e][4], acc[e][5], acc[e][6], acc[e][7]);
    __syncthreads();

    // --- v-net: v[64][16], 4 items/thread ---
    #pragma unroll
    for (int p = 0; p < 4; p++) {
        int item = tid + p * 256;
        int e    = item >> 4;
        int col  = item & 15;
        float a = xv_b2[col];
        #pragma unroll 8
        for (int i4 = 0; i4 < 32; i4++) {
            const float4 hv = *(const float4*)&u.hid[e * HPAD + i4 * 4];
            a = fmaf(hv.x, xv_W2[(i4 * 4 + 0) * 16 + col], a);
            a = fmaf(hv.y, xv_W2[(i4 * 4 + 1) * 16 + col], a);
            a = fmaf(hv.z, xv_W2[(i4 * 4 + 2) * 16 + col], a);
            a = fmaf(hv.w, xv_W2[(i4 * 4 + 3) * 16 + col], a);
        }
        v_s[e][col] = a;
    }
    __syncthreads();

    // --- attention scores + scatter accumulate ---
    {
        const float inv_s8 = 0.35355339059327373f; // 1/sqrt(8)
        const int head = tc2 >> 1;
        const int sub  = tc2 & 1;
        #pragma unroll
        for (int e = 0; e < 8; e++) {
            int el  = te2 * 8 + e;
            int dst = dst_s[el];
            const float4 qv = *(const float4*)&q[(size_t)dst * DD + tc2 * 4];
            float p = qv.x * k_acc[e][0] + qv.y * k_acc[e][1] +
                      qv.z * k_acc[e][2] + qv.w * k_acc[e][3];
            p += __shfl_xor(p, 1);
            if (sub == 0) {
                float ex = expf(p * inv_s8);
                float vw = v_s[el][head] * ew_s[el] * ex;
                float* base = &accN[(((size_t)dst * NHD) + head) * 4];
                atomicAdd(base + 0, vw * rel_s[el][0]);
                atomicAdd(base + 1, vw * rel_s[el][1]);
                atomicAdd(base + 2, vw * rel_s[el][2]);
                atomicAdd(base + 3, ex);
            }
        }
    }
}

// ---------------------------------------------------------------------------
// Kernel 3: out[n] = mean_h num[n][h]/den[n][h]
// ---------------------------------------------------------------------------
__global__ __launch_bounds__(256) void finalize_kernel(
    const float* __restrict__ accN, float* __restrict__ out)
{
    int n = blockIdx.x * blockDim.x + threadIdx.x;
    if (n >= NN) return;
    float ox = 0.0f, oy = 0.0f, oz = 0.0f;
    #pragma unroll
    for (int hh = 0; hh < NHD; hh++) {
        float4 a = *(const float4*)&accN[(((size_t)n * NHD) + hh) * 4];
        if (a.w > 0.0f) {
            float r = 1.0f / a.w;
            ox = fmaf(a.x, r, ox);
            oy = fmaf(a.y, r, oy);
            oz = fmaf(a.z, r, oz);
        }
    }
    out[n * 3 + 0] = ox * (1.0f / NHD);
    out[n * 3 + 1] = oy * (1.0f / NHD);
    out[n * 3 + 2] = oz * (1.0f / NHD);
}

extern "C" void kernel_launch(void* const* d_in, const int* in_sizes, int n_in,
                              void* d_out, int out_size, void* d_ws, size_t ws_size,
                              hipStream_t stream)
{
    const float* h         = (const float*)d_in[0];
    const float* rel_x     = (const float*)d_in[1];
    const float* r_feat    = (const float*)d_in[2];
    const float* edge_feat = (const float*)d_in[3];
    const int*   e_idx     = (const int*)d_in[4];
    const float* xk_W1 = (const float*)d_in[5];
    const float* xk_b1 = (const float*)d_in[6];
    const float* xk_g  = (const float*)d_in[7];
    const float* xk_be = (const float*)d_in[8];
    const float* xk_W2 = (const float*)d_in[9];
    const float* xk_b2 = (const float*)d_in[10];
    const float* xv_W1 = (const float*)d_in[11];
    const float* xv_b1 = (const float*)d_in[12];
    const float* xv_g  = (const float*)d_in[13];
    const float* xv_be = (const float*)d_in[14];
    const float* xv_W2 = (const float*)d_in[15];
    const float* xv_b2 = (const float*)d_in[16];
    const float* xq_W1 = (const float*)d_in[17];
    const float* xq_b1 = (const float*)d_in[18];
    const float* xq_g  = (const float*)d_in[19];
    const float* xq_be = (const float*)d_in[20];
    const float* xq_W2 = (const float*)d_in[21];
    const float* xq_b2 = (const float*)d_in[22];
    const float* ew_W  = (const float*)d_in[23];
    const float* ew_b  = (const float*)d_in[24];

    float* q    = (float*)d_ws;                 // NN*128 floats
    float* accN = q + (size_t)NN * DD;          // NN*16*4 floats

    hipMemsetAsync(accN, 0, (size_t)NN * NHD * 4 * sizeof(float), stream);

    qmlp_kernel<<<NN / 4, 128, 0, stream>>>(h, xq_W1, xq_b1, xq_g, xq_be,
                                            xq_W2, xq_b2, q);

    edge_kernel<<<NE / ME, 256, 0, stream>>>(
        h, rel_x, r_feat, edge_feat,
        e_idx, e_idx + NE,
        xk_W1, xk_b1, xk_g, xk_be, xk_W2, xk_b2,
        xv_W1, xv_b1, xv_g, xv_be, xv_W2, xv_b2,
        ew_W, ew_b, q, accN);

    finalize_kernel<<<(NN + 255) / 256, 256, 0, stream>>>(accN, (float*)d_out);
}

// Round 3
// 1652.024 us; speedup vs baseline: 4.5019x; 3.7921x over previous
//
#include <hip/hip_runtime.h>
#include <hip/hip_bf16.h>

#define NN 50000
#define NE 800000
#define DD 128
#define NHD 16
#define EFD 16
#define RFD 64
#define KVD 336    // real K
#define KP  352    // K padded to 11 * 32 (zeros in 336..351)
#define KST 360    // kv/Wt row stride in bf16 elems (720 B, even bank spread)
#define ME 64
#define HPAD 132   // hid fp32 row stride

typedef __attribute__((ext_vector_type(8))) short bf16x8;
typedef __attribute__((ext_vector_type(4))) float f32x4;

__device__ __forceinline__ unsigned short f2bf(float f) {
    __hip_bfloat16 h = __float2bfloat16(f);   // RNE
    return __builtin_bit_cast(unsigned short, h);
}
__device__ __forceinline__ float bf2f(unsigned short u) {
    return __uint_as_float(((unsigned)u) << 16);
}

// ---------------------------------------------------------------------------
// Prep: W1s -> bf16 transposed Wt[col 0..255][k 0..359] (zeros past 335)
// ---------------------------------------------------------------------------
__global__ __launch_bounds__(256) void prep_wt(
    const float* __restrict__ xkW1, const float* __restrict__ xvW1,
    unsigned short* __restrict__ Wt)
{
    const int n = blockIdx.x;            // 0..255
    const float* W = (n < 128) ? xkW1 : xvW1;
    const int col = n & 127;
    for (int k = threadIdx.x; k < KST; k += 256) {
        float v = (k < KVD) ? W[(size_t)k * 128 + col] : 0.0f;
        Wt[(size_t)n * KST + k] = f2bf(v);
    }
}

// ---------------------------------------------------------------------------
// Prep: h -> bf16 copy
// ---------------------------------------------------------------------------
__global__ __launch_bounds__(256) void prep_hbf(
    const float* __restrict__ h, unsigned short* __restrict__ hb)
{
    const size_t i = ((size_t)blockIdx.x * 256 + threadIdx.x) * 4;
    const float4 f = *(const float4*)&h[i];
    ushort4 o;
    o.x = f2bf(f.x); o.y = f2bf(f.y); o.z = f2bf(f.z); o.w = f2bf(f.w);
    *(ushort4*)&hb[i] = o;
}

// ---------------------------------------------------------------------------
// Kernel 1: q = MLP_xq(h), fp32 compute, bf16 output. 4 nodes / 128 threads.
// ---------------------------------------------------------------------------
__global__ __launch_bounds__(128) void qmlp_kernel(
    const float* __restrict__ h,
    const float* __restrict__ W1, const float* __restrict__ b1,
    const float* __restrict__ g,  const float* __restrict__ be,
    const float* __restrict__ W2, const float* __restrict__ b2,
    unsigned short* __restrict__ q_bf)
{
    __shared__ float hs[4][DD];
    __shared__ float hid[4][DD];
    __shared__ float red[4][2][2];
    const int j  = threadIdx.x;
    const int n0 = blockIdx.x * 4;

    #pragma unroll
    for (int n = 0; n < 4; n++) hs[n][j] = h[(size_t)(n0 + n) * DD + j];
    __syncthreads();

    float a[4];
    #pragma unroll
    for (int n = 0; n < 4; n++) a[n] = b1[j];
    #pragma unroll 8
    for (int i = 0; i < DD; i++) {
        float w = W1[i * DD + j];
        #pragma unroll
        for (int n = 0; n < 4; n++) a[n] = fmaf(hs[n][i], w, a[n]);
    }

    const int wid = j >> 6;
    #pragma unroll
    for (int n = 0; n < 4; n++) {
        float s1 = a[n], s2 = a[n] * a[n];
        #pragma unroll
        for (int off = 32; off > 0; off >>= 1) {
            s1 += __shfl_xor(s1, off);
            s2 += __shfl_xor(s2, off);
        }
        if ((j & 63) == 0) { red[n][0][wid] = s1; red[n][1][wid] = s2; }
    }
    __syncthreads();

    const float gg = g[j], bb = be[j];
    #pragma unroll
    for (int n = 0; n < 4; n++) {
        float s1   = red[n][0][0] + red[n][0][1];
        float s2   = red[n][1][0] + red[n][1][1];
        float mean = s1 * (1.0f / DD);
        float var  = s2 * (1.0f / DD) - mean * mean;
        float r    = (a[n] - mean) * rsqrtf(var + 1e-5f) * gg + bb;
        hid[n][j]  = fmaxf(r, 0.0f);
    }
    __syncthreads();

    float o[4];
    #pragma unroll
    for (int n = 0; n < 4; n++) o[n] = b2[j];
    #pragma unroll 8
    for (int i = 0; i < DD; i++) {
        float w = W2[i * DD + j];
        #pragma unroll
        for (int n = 0; n < 4; n++) o[n] = fmaf(hid[n][i], w, o[n]);
    }
    #pragma unroll
    for (int n = 0; n < 4; n++) q_bf[(size_t)(n0 + n) * DD + j] = f2bf(o[n]);
}

// ---------------------------------------------------------------------------
// Kernel 2: per-edge pipeline, 64 edges / 256 threads.
//  Stage kv bf16 [64][352] ONCE (coalesced row bursts) ->
//  GEMM1 via MFMA 16x16x32 bf16 (wave = 32 edges x 128 cols) ->
//  in-wave LN -> hid fp32 to LDS (k-half, then v-half; union with kv) ->
//  fp32 GEMM2-k / v-net / scores / atomics.
// ---------------------------------------------------------------------------
union SharedU {
    unsigned short kv[ME * KST];   // 46080 B
    float hid[ME * HPAD];          // 33792 B
};

__global__ __launch_bounds__(256, 3) void edge_kernel(
    const unsigned short* __restrict__ h_bf,
    const float* __restrict__ rel_x,
    const float* __restrict__ r_feat,
    const float* __restrict__ edge_feat,
    const int*   __restrict__ e_src,
    const int*   __restrict__ e_dst,
    const unsigned short* __restrict__ Wt,
    const float* __restrict__ xk_b1, const float* __restrict__ xk_g,
    const float* __restrict__ xk_be,
    const float* __restrict__ xk_W2, const float* __restrict__ xk_b2,
    const float* __restrict__ xv_b1, const float* __restrict__ xv_g,
    const float* __restrict__ xv_be,
    const float* __restrict__ xv_W2, const float* __restrict__ xv_b2,
    const float* __restrict__ ew_W,  const float* __restrict__ ew_b,
    const unsigned short* __restrict__ q_bf,
    float* __restrict__ accN)     // [NN][NHD][4] = {x,y,z,den}
{
    __shared__ SharedU u;
    __shared__ float v_s[ME][NHD];
    __shared__ float ew_s[ME];
    __shared__ float rel_s[ME][3];
    __shared__ int   dst_s[ME];
    __shared__ int   src_s[ME];

    const int tid = threadIdx.x;
    const int e0  = blockIdx.x * ME;

    if (tid < ME) { dst_s[tid] = e_dst[e0 + tid]; src_s[tid] = e_src[e0 + tid]; }
    else {
        int t = tid - ME;   // 0..191
        rel_s[t / 3][t % 3] = rel_x[(size_t)e0 * 3 + t];
    }
    __syncthreads();

    // --- stage kv tile once (4 threads per edge) + e_w fused ---
    {
        const int e = tid >> 2, p = tid & 3;
        const size_t ge = (size_t)(e0 + e);
        {   // edge_feat -> cols 0..15
            float4 f = *(const float4*)&edge_feat[ge * EFD + p * 4];
            ushort4 o; o.x = f2bf(f.x); o.y = f2bf(f.y); o.z = f2bf(f.z); o.w = f2bf(f.w);
            *(ushort4*)&u.kv[e * KST + p * 4] = o;
        }
        {   // r_feat -> cols 16..79, fused ew partial dot
            float part = 0.0f;
            #pragma unroll
            for (int i = 0; i < 4; i++) {
                float4 f = *(const float4*)&r_feat[ge * RFD + p * 16 + i * 4];
                float4 w = *(const float4*)&ew_W[p * 16 + i * 4];
                part += f.x * w.x + f.y * w.y + f.z * w.z + f.w * w.w;
                ushort4 o; o.x = f2bf(f.x); o.y = f2bf(f.y); o.z = f2bf(f.z); o.w = f2bf(f.w);
                *(ushort4*)&u.kv[e * KST + 16 + p * 16 + i * 4] = o;
            }
            part += __shfl_xor(part, 1);
            part += __shfl_xor(part, 2);
            if (p == 0) ew_s[e] = 1.0f / (1.0f + expf(-(part + ew_b[0])));
        }
        {   // h_bf[dst] -> cols 80..207 (64B per thread, 16B chunks)
            const uint4* hp = (const uint4*)&h_bf[(size_t)dst_s[e] * DD + p * 32];
            uint4* op = (uint4*)&u.kv[e * KST + 80 + p * 32];
            #pragma unroll
            for (int i = 0; i < 4; i++) op[i] = hp[i];
        }
        {   // h_bf[src] -> cols 208..335
            const uint4* hp = (const uint4*)&h_bf[(size_t)src_s[e] * DD + p * 32];
            uint4* op = (uint4*)&u.kv[e * KST + 208 + p * 32];
            #pragma unroll
            for (int i = 0; i < 4; i++) op[i] = hp[i];
        }
        if (p < 2) {   // zero K-tail 336..351
            uint4 z = make_uint4(0, 0, 0, 0);
            *(uint4*)&u.kv[e * KST + 336 + p * 8] = z;
        }
    }
    __syncthreads();

    // --- GEMM1: MFMA. wave w: edges (w&1)*32..+31, cols (w>>1)*128..+127 ---
    const int lane = tid & 63;
    const int wv   = tid >> 6;
    const int half = wv >> 1;          // 0 = xk, 1 = xv
    const int mrow = (wv & 1) * 32;    // edge base
    const int c15  = lane & 15;
    const int q    = lane >> 4;

    f32x4 acc[2][8];
    #pragma unroll
    for (int mt = 0; mt < 2; mt++)
        #pragma unroll
        for (int nt = 0; nt < 8; nt++) acc[mt][nt] = (f32x4){0.f, 0.f, 0.f, 0.f};

    {
        const unsigned short* WtH = Wt + (size_t)(half * 128 + c15) * KST;
        const unsigned short* kvA = &u.kv[(mrow + c15) * KST];
        for (int ks = 0; ks < 11; ks++) {
            const int k0 = ks * 32 + q * 8;
            bf16x8 a0 = *(const bf16x8*)&kvA[k0];
            bf16x8 a1 = *(const bf16x8*)&kvA[16 * KST + k0];
            #pragma unroll
            for (int nt = 0; nt < 8; nt++) {
                bf16x8 b = *(const bf16x8*)&WtH[(size_t)nt * 16 * KST + k0];
                acc[0][nt] = __builtin_amdgcn_mfma_f32_16x16x32_bf16(a0, b, acc[0][nt], 0, 0, 0);
                acc[1][nt] = __builtin_amdgcn_mfma_f32_16x16x32_bf16(a1, b, acc[1][nt], 0, 0, 0);
            }
        }
    }

    // --- bias + LayerNorm + ReLU, fully in-wave (16-lane groups share a row) ---
    {
        const float* b1p = half ? xv_b1 : xk_b1;
        const float* gp  = half ? xv_g  : xk_g;
        const float* bep = half ? xv_be : xk_be;
        float bia[8], gam[8], bet[8];
        #pragma unroll
        for (int nt = 0; nt < 8; nt++) {
            int idx = nt * 16 + c15;
            bia[nt] = b1p[idx]; gam[nt] = gp[idx]; bet[nt] = bep[idx];
        }
        #pragma unroll
        for (int mt = 0; mt < 2; mt++)
            #pragma unroll
            for (int r = 0; r < 4; r++) {
                float x[8]; float s1 = 0.f, s2 = 0.f;
                #pragma unroll
                for (int nt = 0; nt < 8; nt++) {
                    x[nt] = acc[mt][nt][r] + bia[nt];
                    s1 += x[nt]; s2 = fmaf(x[nt], x[nt], s2);
                }
                #pragma unroll
                for (int off = 1; off < 16; off <<= 1) {
                    s1 += __shfl_xor(s1, off);
                    s2 += __shfl_xor(s2, off);
                }
                float mean = s1 * (1.0f / 128.0f);
                float var  = s2 * (1.0f / 128.0f) - mean * mean;
                float rstd = rsqrtf(var + 1e-5f);
                #pragma unroll
                for (int nt = 0; nt < 8; nt++)
                    acc[mt][nt][r] = fmaxf((x[nt] - mean) * rstd * gam[nt] + bet[nt], 0.0f);
            }
    }
    __syncthreads();   // all kv reads done before hid overwrites the union

    // --- xk waves store hid (k-half), fp32 ---
    if (half == 0) {
        #pragma unroll
        for (int mt = 0; mt < 2; mt++)
            #pragma unroll
            for (int r = 0; r < 4; r++)
                #pragma unroll
                for (int nt = 0; nt < 8; nt++)
                    u.hid[(mrow + mt * 16 + q * 4 + r) * HPAD + nt * 16 + c15] = acc[mt][nt][r];
    }
    __syncthreads();

    // --- GEMM2 k-net fp32: k[64][128], thread = 8 edges x 4 cols ---
    const int tc2 = tid & 31;
    const int te2 = tid >> 5;
    float k_acc[8][4];
    {
        const float4 b2v = *(const float4*)&xk_b2[tc2 * 4];
        #pragma unroll
        for (int e = 0; e < 8; e++) {
            k_acc[e][0] = b2v.x; k_acc[e][1] = b2v.y;
            k_acc[e][2] = b2v.z; k_acc[e][3] = b2v.w;
        }
        #pragma unroll 4
        for (int i4 = 0; i4 < 32; i4++) {
            const float4 w0 = *(const float4*)&xk_W2[(i4 * 4 + 0) * 128 + tc2 * 4];
            const float4 w1 = *(const float4*)&xk_W2[(i4 * 4 + 1) * 128 + tc2 * 4];
            const float4 w2 = *(const float4*)&xk_W2[(i4 * 4 + 2) * 128 + tc2 * 4];
            const float4 w3 = *(const float4*)&xk_W2[(i4 * 4 + 3) * 128 + tc2 * 4];
            #pragma unroll
            for (int e = 0; e < 8; e++) {
                const float4 hv = *(const float4*)&u.hid[(te2 * 8 + e) * HPAD + i4 * 4];
                k_acc[e][0] = fmaf(hv.x, w0.x, k_acc[e][0]);
                k_acc[e][1] = fmaf(hv.x, w0.y, k_acc[e][1]);
                k_acc[e][2] = fmaf(hv.x, w0.z, k_acc[e][2]);
                k_acc[e][3] = fmaf(hv.x, w0.w, k_acc[e][3]);
                k_acc[e][0] = fmaf(hv.y, w1.x, k_acc[e][0]);
                k_acc[e][1] = fmaf(hv.y, w1.y, k_acc[e][1]);
                k_acc[e][2] = fmaf(hv.y, w1.z, k_acc[e][2]);
                k_acc[e][3] = fmaf(hv.y, w1.w, k_acc[e][3]);
                k_acc[e][0] = fmaf(hv.z, w2.x, k_acc[e][0]);
                k_acc[e][1] = fmaf(hv.z, w2.y, k_acc[e][1]);
                k_acc[e][2] = fmaf(hv.z, w2.z, k_acc[e][2]);
                k_acc[e][3] = fmaf(hv.z, w2.w, k_acc[e][3]);
                k_acc[e][0] = fmaf(hv.w, w3.x, k_acc[e][0]);
                k_acc[e][1] = fmaf(hv.w, w3.y, k_acc[e][1]);
                k_acc[e][2] = fmaf(hv.w, w3.z, k_acc[e][2]);
                k_acc[e][3] = fmaf(hv.w, w3.w, k_acc[e][3]);
            }
        }
    }
    __syncthreads();   // k reads done before v-half overwrite

    // --- xv waves store hid (v-half) ---
    if (half == 1) {
        #pragma unroll
        for (int mt = 0; mt < 2; mt++)
            #pragma unroll
            for (int r = 0; r < 4; r++)
                #pragma unroll
                for (int nt = 0; nt < 8; nt++)
                    u.hid[(mrow + mt * 16 + q * 4 + r) * HPAD + nt * 16 + c15] = acc[mt][nt][r];
    }
    __syncthreads();

    // --- v-net fp32: v[64][16], 4 items/thread ---
    #pragma unroll
    for (int p = 0; p < 4; p++) {
        int item = tid + p * 256;
        int e    = item >> 4;
        int col  = item & 15;
        float a = xv_b2[col];
        #pragma unroll 8
        for (int i4 = 0; i4 < 32; i4++) {
            const float4 hv = *(const float4*)&u.hid[e * HPAD + i4 * 4];
            a = fmaf(hv.x, xv_W2[(i4 * 4 + 0) * 16 + col], a);
            a = fmaf(hv.y, xv_W2[(i4 * 4 + 1) * 16 + col], a);
            a = fmaf(hv.z, xv_W2[(i4 * 4 + 2) * 16 + col], a);
            a = fmaf(hv.w, xv_W2[(i4 * 4 + 3) * 16 + col], a);
        }
        v_s[e][col] = a;
    }
    __syncthreads();

    // --- attention scores + scatter accumulate ---
    {
        const float inv_s8 = 0.35355339059327373f; // 1/sqrt(8)
        const int head = tc2 >> 1;
        const int sub  = tc2 & 1;
        #pragma unroll
        for (int e = 0; e < 8; e++) {
            int el  = te2 * 8 + e;
            int dst = dst_s[el];
            const ushort4 qb = *(const ushort4*)&q_bf[(size_t)dst * DD + tc2 * 4];
            float p = bf2f(qb.x) * k_acc[e][0] + bf2f(qb.y) * k_acc[e][1] +
                      bf2f(qb.z) * k_acc[e][2] + bf2f(qb.w) * k_acc[e][3];
            p += __shfl_xor(p, 1);
            if (sub == 0) {
                float ex = expf(p * inv_s8);
                float vw = v_s[el][head] * ew_s[el] * ex;
                float* base = &accN[(((size_t)dst * NHD) + head) * 4];
                atomicAdd(base + 0, vw * rel_s[el][0]);
                atomicAdd(base + 1, vw * rel_s[el][1]);
                atomicAdd(base + 2, vw * rel_s[el][2]);
                atomicAdd(base + 3, ex);
            }
        }
    }
}

// ---------------------------------------------------------------------------
// Kernel 3: out[n] = mean_h num[n][h]/den[n][h]
// ---------------------------------------------------------------------------
__global__ __launch_bounds__(256) void finalize_kernel(
    const float* __restrict__ accN, float* __restrict__ out)
{
    int n = blockIdx.x * blockDim.x + threadIdx.x;
    if (n >= NN) return;
    float ox = 0.0f, oy = 0.0f, oz = 0.0f;
    #pragma unroll
    for (int hh = 0; hh < NHD; hh++) {
        float4 a = *(const float4*)&accN[(((size_t)n * NHD) + hh) * 4];
        if (a.w > 0.0f) {
            float r = 1.0f / a.w;
            ox = fmaf(a.x, r, ox);
            oy = fmaf(a.y, r, oy);
            oz = fmaf(a.z, r, oz);
        }
    }
    out[n * 3 + 0] = ox * (1.0f / NHD);
    out[n * 3 + 1] = oy * (1.0f / NHD);
    out[n * 3 + 2] = oz * (1.0f / NHD);
}

extern "C" void kernel_launch(void* const* d_in, const int* in_sizes, int n_in,
                              void* d_out, int out_size, void* d_ws, size_t ws_size,
                              hipStream_t stream)
{
    const float* h         = (const float*)d_in[0];
    const float* rel_x     = (const float*)d_in[1];
    const float* r_feat    = (const float*)d_in[2];
    const float* edge_feat = (const float*)d_in[3];
    const int*   e_idx     = (const int*)d_in[4];
    const float* xk_W1 = (const float*)d_in[5];
    const float* xk_b1 = (const float*)d_in[6];
    const float* xk_g  = (const float*)d_in[7];
    const float* xk_be = (const float*)d_in[8];
    const float* xk_W2 = (const float*)d_in[9];
    const float* xk_b2 = (const float*)d_in[10];
    const float* xv_W1 = (const float*)d_in[11];
    const float* xv_b1 = (const float*)d_in[12];
    const float* xv_g  = (const float*)d_in[13];
    const float* xv_be = (const float*)d_in[14];
    const float* xv_W2 = (const float*)d_in[15];
    const float* xv_b2 = (const float*)d_in[16];
    const float* xq_W1 = (const float*)d_in[17];
    const float* xq_b1 = (const float*)d_in[18];
    const float* xq_g  = (const float*)d_in[19];
    const float* xq_be = (const float*)d_in[20];
    const float* xq_W2 = (const float*)d_in[21];
    const float* xq_b2 = (const float*)d_in[22];
    const float* ew_W  = (const float*)d_in[23];
    const float* ew_b  = (const float*)d_in[24];

    float* accN = (float*)d_ws;                                  // NN*16*4 f32
    unsigned short* h_bf = (unsigned short*)(accN + (size_t)NN * NHD * 4);
    unsigned short* q_bf = h_bf + (size_t)NN * DD;
    unsigned short* Wt   = q_bf + (size_t)NN * DD;               // 256*360

    hipMemsetAsync(accN, 0, (size_t)NN * NHD * 4 * sizeof(float), stream);

    prep_hbf<<<(NN * DD / 4 + 255) / 256, 256, 0, stream>>>(h, h_bf);
    prep_wt<<<256, 256, 0, stream>>>(xk_W1, xv_W1, Wt);

    qmlp_kernel<<<NN / 4, 128, 0, stream>>>(h, xq_W1, xq_b1, xq_g, xq_be,
                                            xq_W2, xq_b2, q_bf);

    edge_kernel<<<NE / ME, 256, 0, stream>>>(
        h_bf, rel_x, r_feat, edge_feat,
        e_idx, e_idx + NE,
        Wt,
        xk_b1, xk_g, xk_be, xk_W2, xk_b2,
        xv_b1, xv_g, xv_be, xv_W2, xv_b2,
        ew_W, ew_b, q_bf, accN);

    finalize_kernel<<<(NN + 255) / 256, 256, 0, stream>>>(accN, (float*)d_out);
}

// Round 5
// 1422.552 us; speedup vs baseline: 5.2281x; 1.1613x over previous
//
#include <hip/hip_runtime.h>
#include <hip/hip_bf16.h>

#define NN 50000
#define NE 800000
#define DD 128
#define NHD 16
#define EFD 16
#define RFD 64
#define KVD 336    // real K
#define KST 360    // kv/Wt row stride in bf16 elems
#define ME 64
#define HST 136    // hid bf16 row stride (272 B, 16B-aligned rows)
#define KSS 132    // k_s fp32 row stride

typedef __attribute__((ext_vector_type(8))) short bf16x8;
typedef __attribute__((ext_vector_type(4))) float f32x4;

__device__ __forceinline__ unsigned short f2bf(float f) {
    __hip_bfloat16 h = __float2bfloat16(f);   // RNE
    return __builtin_bit_cast(unsigned short, h);
}
__device__ __forceinline__ float bf2f(unsigned short u) {
    return __uint_as_float(((unsigned)u) << 16);
}

// ---------------------------------------------------------------------------
// Prep: W1s -> bf16 transposed Wt[col 0..255][k 0..359] (zeros past 335)
// ---------------------------------------------------------------------------
__global__ __launch_bounds__(256) void prep_wt(
    const float* __restrict__ xkW1, const float* __restrict__ xvW1,
    unsigned short* __restrict__ Wt)
{
    const int n = blockIdx.x;            // 0..255
    const float* W = (n < 128) ? xkW1 : xvW1;
    const int col = n & 127;
    for (int k = threadIdx.x; k < KST; k += 256) {
        float v = (k < KVD) ? W[(size_t)k * 128 + col] : 0.0f;
        Wt[(size_t)n * KST + k] = f2bf(v);
    }
}

// ---------------------------------------------------------------------------
// Prep: W2s -> bf16 transposed Wt2[n 0..143][k 0..127]
//   rows 0..127 = xk_W2 columns; rows 128..143 = xv_W2 columns
// ---------------------------------------------------------------------------
__global__ __launch_bounds__(128) void prep_wt2(
    const float* __restrict__ xkW2, const float* __restrict__ xvW2,
    unsigned short* __restrict__ Wt2)
{
    const int n = blockIdx.x;            // 0..143
    const int k = threadIdx.x;           // 0..127
    float v = (n < 128) ? xkW2[(size_t)k * 128 + n]
                        : xvW2[(size_t)k * 16 + (n - 128)];
    Wt2[(size_t)n * 128 + k] = f2bf(v);
}

// ---------------------------------------------------------------------------
// Prep: h -> bf16 copy
// ---------------------------------------------------------------------------
__global__ __launch_bounds__(256) void prep_hbf(
    const float* __restrict__ h, unsigned short* __restrict__ hb)
{
    const size_t i = ((size_t)blockIdx.x * 256 + threadIdx.x) * 4;
    const float4 f = *(const float4*)&h[i];
    ushort4 o;
    o.x = f2bf(f.x); o.y = f2bf(f.y); o.z = f2bf(f.z); o.w = f2bf(f.w);
    *(ushort4*)&hb[i] = o;
}

// ---------------------------------------------------------------------------
// Kernel 1: q = MLP_xq(h), fp32 compute, bf16 output. 4 nodes / 128 threads.
// ---------------------------------------------------------------------------
__global__ __launch_bounds__(128) void qmlp_kernel(
    const float* __restrict__ h,
    const float* __restrict__ W1, const float* __restrict__ b1,
    const float* __restrict__ g,  const float* __restrict__ be,
    const float* __restrict__ W2, const float* __restrict__ b2,
    unsigned short* __restrict__ q_bf)
{
    __shared__ float hs[4][DD];
    __shared__ float hid[4][DD];
    __shared__ float red[4][2][2];
    const int j  = threadIdx.x;
    const int n0 = blockIdx.x * 4;

    #pragma unroll
    for (int n = 0; n < 4; n++) hs[n][j] = h[(size_t)(n0 + n) * DD + j];
    __syncthreads();

    float a[4];
    #pragma unroll
    for (int n = 0; n < 4; n++) a[n] = b1[j];
    #pragma unroll 8
    for (int i = 0; i < DD; i++) {
        float w = W1[i * DD + j];
        #pragma unroll
        for (int n = 0; n < 4; n++) a[n] = fmaf(hs[n][i], w, a[n]);
    }

    const int wid = j >> 6;
    #pragma unroll
    for (int n = 0; n < 4; n++) {
        float s1 = a[n], s2 = a[n] * a[n];
        #pragma unroll
        for (int off = 32; off > 0; off >>= 1) {
            s1 += __shfl_xor(s1, off);
            s2 += __shfl_xor(s2, off);
        }
        if ((j & 63) == 0) { red[n][0][wid] = s1; red[n][1][wid] = s2; }
    }
    __syncthreads();

    const float gg = g[j], bb = be[j];
    #pragma unroll
    for (int n = 0; n < 4; n++) {
        float s1   = red[n][0][0] + red[n][0][1];
        float s2   = red[n][1][0] + red[n][1][1];
        float mean = s1 * (1.0f / DD);
        float var  = s2 * (1.0f / DD) - mean * mean;
        float r    = (a[n] - mean) * rsqrtf(var + 1e-5f) * gg + bb;
        hid[n][j]  = fmaxf(r, 0.0f);
    }
    __syncthreads();

    float o[4];
    #pragma unroll
    for (int n = 0; n < 4; n++) o[n] = b2[j];
    #pragma unroll 8
    for (int i = 0; i < DD; i++) {
        float w = W2[i * DD + j];
        #pragma unroll
        for (int n = 0; n < 4; n++) o[n] = fmaf(hid[n][i], w, o[n]);
    }
    #pragma unroll
    for (int n = 0; n < 4; n++) q_bf[(size_t)(n0 + n) * DD + j] = f2bf(o[n]);
}

// ---------------------------------------------------------------------------
// Kernel 2: per-edge pipeline, 64 edges / 256 threads.
//  Stage kv bf16 [64][352] once -> GEMM1 MFMA -> in-wave LN ->
//  hid (k+v halves) bf16 to LDS -> GEMM2-k MFMA (Wt2 B-frags from L2) +
//  v-net fp32 VALU -> k_s fp32 to LDS -> scores + atomics.
// ---------------------------------------------------------------------------
union SharedU {
    unsigned short kv[ME * KST];            // 46080 B
    struct {
        unsigned short hidk[ME * HST];      // 17408 B
        unsigned short hidv[ME * HST];      // 17408 B
    } s2;
    float ks[ME * KSS];                     // 33792 B
};

__global__ __launch_bounds__(256, 3) void edge_kernel(
    const unsigned short* __restrict__ h_bf,
    const float* __restrict__ rel_x,
    const float* __restrict__ r_feat,
    const float* __restrict__ edge_feat,
    const int*   __restrict__ e_src,
    const int*   __restrict__ e_dst,
    const unsigned short* __restrict__ Wt,
    const unsigned short* __restrict__ Wt2,
    const float* __restrict__ xk_b1, const float* __restrict__ xk_g,
    const float* __restrict__ xk_be, const float* __restrict__ xk_b2,
    const float* __restrict__ xv_b1, const float* __restrict__ xv_g,
    const float* __restrict__ xv_be, const float* __restrict__ xv_W2,
    const float* __restrict__ xv_b2,
    const float* __restrict__ ew_W,  const float* __restrict__ ew_b,
    const unsigned short* __restrict__ q_bf,
    float* __restrict__ accN)     // [NN][NHD][4] = {x,y,z,den}
{
    __shared__ SharedU u;
    __shared__ float v_s[ME][NHD + 1];
    __shared__ float ew_s[ME];
    __shared__ float rel_s[ME][3];
    __shared__ int   dst_s[ME];
    __shared__ int   src_s[ME];

    const int tid = threadIdx.x;
    const int e0  = blockIdx.x * ME;

    if (tid < ME) { dst_s[tid] = e_dst[e0 + tid]; src_s[tid] = e_src[e0 + tid]; }
    else {
        int t = tid - ME;   // 0..191
        rel_s[t / 3][t % 3] = rel_x[(size_t)e0 * 3 + t];
    }
    __syncthreads();

    // --- stage kv tile once (4 threads per edge) + e_w fused ---
    {
        const int e = tid >> 2, p = tid & 3;
        const size_t ge = (size_t)(e0 + e);
        {   // edge_feat -> cols 0..15
            float4 f = *(const float4*)&edge_feat[ge * EFD + p * 4];
            ushort4 o; o.x = f2bf(f.x); o.y = f2bf(f.y); o.z = f2bf(f.z); o.w = f2bf(f.w);
            *(ushort4*)&u.kv[e * KST + p * 4] = o;
        }
        {   // r_feat -> cols 16..79, fused ew partial dot
            float part = 0.0f;
            #pragma unroll
            for (int i = 0; i < 4; i++) {
                float4 f = *(const float4*)&r_feat[ge * RFD + p * 16 + i * 4];
                float4 w = *(const float4*)&ew_W[p * 16 + i * 4];
                part += f.x * w.x + f.y * w.y + f.z * w.z + f.w * w.w;
                ushort4 o; o.x = f2bf(f.x); o.y = f2bf(f.y); o.z = f2bf(f.z); o.w = f2bf(f.w);
                *(ushort4*)&u.kv[e * KST + 16 + p * 16 + i * 4] = o;
            }
            part += __shfl_xor(part, 1);
            part += __shfl_xor(part, 2);
            if (p == 0) ew_s[e] = 1.0f / (1.0f + expf(-(part + ew_b[0])));
        }
        {   // h_bf[dst] -> cols 80..207
            const uint4* hp = (const uint4*)&h_bf[(size_t)dst_s[e] * DD + p * 32];
            uint4* op = (uint4*)&u.kv[e * KST + 80 + p * 32];
            #pragma unroll
            for (int i = 0; i < 4; i++) op[i] = hp[i];
        }
        {   // h_bf[src] -> cols 208..335
            const uint4* hp = (const uint4*)&h_bf[(size_t)src_s[e] * DD + p * 32];
            uint4* op = (uint4*)&u.kv[e * KST + 208 + p * 32];
            #pragma unroll
            for (int i = 0; i < 4; i++) op[i] = hp[i];
        }
        if (p < 2) {   // zero K-tail 336..351
            uint4 z = make_uint4(0, 0, 0, 0);
            *(uint4*)&u.kv[e * KST + 336 + p * 8] = z;
        }
    }
    __syncthreads();

    // --- GEMM1: MFMA. wave w: edges (w&1)*32..+31, cols (w>>1)*128..+127 ---
    const int lane = tid & 63;
    const int wv   = tid >> 6;
    const int half = wv >> 1;          // 0 = xk, 1 = xv
    const int mrow = (wv & 1) * 32;    // edge base
    const int c15  = lane & 15;
    const int q    = lane >> 4;

    f32x4 acc[2][8];
    #pragma unroll
    for (int mt = 0; mt < 2; mt++)
        #pragma unroll
        for (int nt = 0; nt < 8; nt++) acc[mt][nt] = (f32x4){0.f, 0.f, 0.f, 0.f};

    {
        const unsigned short* WtH = Wt + (size_t)(half * 128 + c15) * KST;
        const unsigned short* kvA = &u.kv[(mrow + c15) * KST];
        for (int ks = 0; ks < 11; ks++) {
            const int k0 = ks * 32 + q * 8;
            bf16x8 a0 = *(const bf16x8*)&kvA[k0];
            bf16x8 a1 = *(const bf16x8*)&kvA[16 * KST + k0];
            #pragma unroll
            for (int nt = 0; nt < 8; nt++) {
                bf16x8 b = *(const bf16x8*)&WtH[(size_t)nt * 16 * KST + k0];
                acc[0][nt] = __builtin_amdgcn_mfma_f32_16x16x32_bf16(a0, b, acc[0][nt], 0, 0, 0);
                acc[1][nt] = __builtin_amdgcn_mfma_f32_16x16x32_bf16(a1, b, acc[1][nt], 0, 0, 0);
            }
        }
    }

    // --- bias + LayerNorm + ReLU, fully in-wave (16-lane groups share a row) ---
    {
        const float* b1p = half ? xv_b1 : xk_b1;
        const float* gp  = half ? xv_g  : xk_g;
        const float* bep = half ? xv_be : xk_be;
        float bia[8], gam[8], bet[8];
        #pragma unroll
        for (int nt = 0; nt < 8; nt++) {
            int idx = nt * 16 + c15;
            bia[nt] = b1p[idx]; gam[nt] = gp[idx]; bet[nt] = bep[idx];
        }
        #pragma unroll
        for (int mt = 0; mt < 2; mt++)
            #pragma unroll
            for (int r = 0; r < 4; r++) {
                float x[8]; float s1 = 0.f, s2 = 0.f;
                #pragma unroll
                for (int nt = 0; nt < 8; nt++) {
                    x[nt] = acc[mt][nt][r] + bia[nt];
                    s1 += x[nt]; s2 = fmaf(x[nt], x[nt], s2);
                }
                #pragma unroll
                for (int off = 1; off < 16; off <<= 1) {
                    s1 += __shfl_xor(s1, off);
                    s2 += __shfl_xor(s2, off);
                }
                float mean = s1 * (1.0f / 128.0f);
                float var  = s2 * (1.0f / 128.0f) - mean * mean;
                float rstd = rsqrtf(var + 1e-5f);
                #pragma unroll
                for (int nt = 0; nt < 8; nt++)
                    acc[mt][nt][r] = fmaxf((x[nt] - mean) * rstd * gam[nt] + bet[nt], 0.0f);
            }
    }
    __syncthreads();   // all kv reads done before hid overwrites the union

    // --- store hid bf16: xk waves -> hidk, xv waves -> hidv ---
    {
        unsigned short* hdst = half ? u.s2.hidv : u.s2.hidk;
        #pragma unroll
        for (int mt = 0; mt < 2; mt++)
            #pragma unroll
            for (int r = 0; r < 4; r++) {
                const int row = mrow + mt * 16 + q * 4 + r;
                #pragma unroll
                for (int nt = 0; nt < 8; nt++)
                    hdst[row * HST + nt * 16 + c15] = f2bf(acc[mt][nt][r]);
            }
    }
    __syncthreads();

    // --- GEMM2-k via MFMA: M=64 edges, N=128, K=128 ---
    // wave w: edges (w&1)*32..+31, cols (w>>1)*64..+63
    const int mb2 = (wv & 1) * 32;
    const int nb2 = (wv >> 1) * 64;
    f32x4 acck[2][4];
    #pragma unroll
    for (int mt = 0; mt < 2; mt++)
        #pragma unroll
        for (int nt = 0; nt < 4; nt++) acck[mt][nt] = (f32x4){0.f, 0.f, 0.f, 0.f};
    {
        const unsigned short* A0 = &u.s2.hidk[(mb2 + c15) * HST];
        const unsigned short* A1 = &u.s2.hidk[(mb2 + 16 + c15) * HST];
        const unsigned short* B0 = &Wt2[(size_t)(nb2 + c15) * 128];
        #pragma unroll
        for (int ks = 0; ks < 4; ks++) {
            const int k0 = ks * 32 + q * 8;
            bf16x8 a0 = *(const bf16x8*)&A0[k0];
            bf16x8 a1 = *(const bf16x8*)&A1[k0];
            #pragma unroll
            for (int nt = 0; nt < 4; nt++) {
                bf16x8 b = *(const bf16x8*)&B0[(size_t)nt * 16 * 128 + k0];
                acck[0][nt] = __builtin_amdgcn_mfma_f32_16x16x32_bf16(a0, b, acck[0][nt], 0, 0, 0);
                acck[1][nt] = __builtin_amdgcn_mfma_f32_16x16x32_bf16(a1, b, acck[1][nt], 0, 0, 0);
            }
        }
    }

    // --- v-net fp32 VALU (W2v exact), reads bf16 hidv: v[64][16] ---
    float vacc[4];
    #pragma unroll
    for (int p = 0; p < 4; p++) {
        int item = tid + p * 256;
        int e    = item >> 4;
        int col  = item & 15;
        float a = xv_b2[col];
        #pragma unroll 8
        for (int i4 = 0; i4 < 32; i4++) {
            const ushort4 hv = *(const ushort4*)&u.s2.hidv[e * HST + i4 * 4];
            a = fmaf(bf2f(hv.x), xv_W2[(i4 * 4 + 0) * 16 + col], a);
            a = fmaf(bf2f(hv.y), xv_W2[(i4 * 4 + 1) * 16 + col], a);
            a = fmaf(bf2f(hv.z), xv_W2[(i4 * 4 + 2) * 16 + col], a);
            a = fmaf(bf2f(hv.w), xv_W2[(i4 * 4 + 3) * 16 + col], a);
        }
        vacc[p] = a;
    }
    __syncthreads();   // hid reads done before ks overwrite

    // --- store k (bias folded) fp32 to LDS + v_s ---
    #pragma unroll
    for (int nt = 0; nt < 4; nt++) {
        const float bias = xk_b2[nb2 + nt * 16 + c15];
        #pragma unroll
        for (int mt = 0; mt < 2; mt++)
            #pragma unroll
            for (int r = 0; r < 4; r++)
                u.ks[(mb2 + mt * 16 + q * 4 + r) * KSS + nb2 + nt * 16 + c15] =
                    acck[mt][nt][r] + bias;
    }
    #pragma unroll
    for (int p = 0; p < 4; p++) {
        int item = tid + p * 256;
        v_s[item >> 4][item & 15] = vacc[p];
    }
    __syncthreads();

    // --- attention scores + scatter accumulate ---
    {
        const float inv_s8 = 0.35355339059327373f; // 1/sqrt(8)
        const int tc2  = tid & 31;
        const int te2  = tid >> 5;
        const int head = tc2 >> 1;
        const int sub  = tc2 & 1;
        #pragma unroll
        for (int e = 0; e < 8; e++) {
            int el  = te2 * 8 + e;
            int dst = dst_s[el];
            const float4  kk = *(const float4*)&u.ks[el * KSS + tc2 * 4];
            const ushort4 qb = *(const ushort4*)&q_bf[(size_t)dst * DD + tc2 * 4];
            float p = bf2f(qb.x) * kk.x + bf2f(qb.y) * kk.y +
                      bf2f(qb.z) * kk.z + bf2f(qb.w) * kk.w;
            p += __shfl_xor(p, 1);
            if (sub == 0) {
                float ex = expf(p * inv_s8);
                float vw = v_s[el][head] * ew_s[el] * ex;
                float* base = &accN[(((size_t)dst * NHD) + head) * 4];
                atomicAdd(base + 0, vw * rel_s[el][0]);
                atomicAdd(base + 1, vw * rel_s[el][1]);
                atomicAdd(base + 2, vw * rel_s[el][2]);
                atomicAdd(base + 3, ex);
            }
        }
    }
}

// ---------------------------------------------------------------------------
// Kernel 3: out[n] = mean_h num[n][h]/den[n][h]
// ---------------------------------------------------------------------------
__global__ __launch_bounds__(256) void finalize_kernel(
    const float* __restrict__ accN, float* __restrict__ out)
{
    int n = blockIdx.x * blockDim.x + threadIdx.x;
    if (n >= NN) return;
    float ox = 0.0f, oy = 0.0f, oz = 0.0f;
    #pragma unroll
    for (int hh = 0; hh < NHD; hh++) {
        float4 a = *(const float4*)&accN[(((size_t)n * NHD) + hh) * 4];
        if (a.w > 0.0f) {
            float r = 1.0f / a.w;
            ox = fmaf(a.x, r, ox);
            oy = fmaf(a.y, r, oy);
            oz = fmaf(a.z, r, oz);
        }
    }
    out[n * 3 + 0] = ox * (1.0f / NHD);
    out[n * 3 + 1] = oy * (1.0f / NHD);
    out[n * 3 + 2] = oz * (1.0f / NHD);
}

extern "C" void kernel_launch(void* const* d_in, const int* in_sizes, int n_in,
                              void* d_out, int out_size, void* d_ws, size_t ws_size,
                              hipStream_t stream)
{
    const float* h         = (const float*)d_in[0];
    const float* rel_x     = (const float*)d_in[1];
    const float* r_feat    = (const float*)d_in[2];
    const float* edge_feat = (const float*)d_in[3];
    const int*   e_idx     = (const int*)d_in[4];
    const float* xk_W1 = (const float*)d_in[5];
    const float* xk_b1 = (const float*)d_in[6];
    const float* xk_g  = (const float*)d_in[7];
    const float* xk_be = (const float*)d_in[8];
    const float* xk_W2 = (const float*)d_in[9];
    const float* xk_b2 = (const float*)d_in[10];
    const float* xv_W1 = (const float*)d_in[11];
    const float* xv_b1 = (const float*)d_in[12];
    const float* xv_g  = (const float*)d_in[13];
    const float* xv_be = (const float*)d_in[14];
    const float* xv_W2 = (const float*)d_in[15];
    const float* xv_b2 = (const float*)d_in[16];
    const float* xq_W1 = (const float*)d_in[17];
    const float* xq_b1 = (const float*)d_in[18];
    const float* xq_g  = (const float*)d_in[19];
    const float* xq_be = (const float*)d_in[20];
    const float* xq_W2 = (const float*)d_in[21];
    const float* xq_b2 = (const float*)d_in[22];
    const float* ew_W  = (const float*)d_in[23];
    const float* ew_b  = (const float*)d_in[24];

    float* accN = (float*)d_ws;                                  // NN*16*4 f32
    unsigned short* h_bf = (unsigned short*)(accN + (size_t)NN * NHD * 4);
    unsigned short* q_bf = h_bf + (size_t)NN * DD;
    unsigned short* Wt   = q_bf + (size_t)NN * DD;               // 256*360
    unsigned short* Wt2  = Wt + (size_t)256 * KST;               // 144*128

    hipMemsetAsync(accN, 0, (size_t)NN * NHD * 4 * sizeof(float), stream);

    prep_hbf<<<(NN * DD / 4 + 255) / 256, 256, 0, stream>>>(h, h_bf);
    prep_wt<<<256, 256, 0, stream>>>(xk_W1, xv_W1, Wt);
    prep_wt2<<<144, 128, 0, stream>>>(xk_W2, xv_W2, Wt2);

    qmlp_kernel<<<NN / 4, 128, 0, stream>>>(h, xq_W1, xq_b1, xq_g, xq_be,
                                            xq_W2, xq_b2, q_bf);

    edge_kernel<<<NE / ME, 256, 0, stream>>>(
        h_bf, rel_x, r_feat, edge_feat,
        e_idx, e_idx + NE,
        Wt, Wt2,
        xk_b1, xk_g, xk_be, xk_b2,
        xv_b1, xv_g, xv_be, xv_W2, xv_b2,
        ew_W, ew_b, q_bf, accN);

    finalize_kernel<<<(NN + 255) / 256, 256, 0, stream>>>(accN, (float*)d_out);
}